// Round 17
// baseline (17.179 us; speedup 1.0000x reference)
//
#include <hip/hip_runtime.h>
#include <math.h>

#define N_G   4096
#define IMW   96
#define TILE  6             // 6x6 px tiles
#define TILES_X 16
#define NTILE (TILES_X*TILES_X)   // 256 blocks == 256 CUs
#define NTHR  1024          // 16 waves per block
#define NW    (NTHR/64)
#define NPX   (TILE*TILE)   // 36 pixels per tile
#define NSEG  16            // depth segments per pixel == NW
#define CAP   512           // max survivors per tile
#define FXI   (1.0f/96.0f)
#define NEARP 0.3f
#define EPSV  1e-8f
#define LOG2E 1.4426950408889634f
#define CULL_K 26.0f        // drop alpha < opa * 2^-26 within tile

typedef unsigned long long ull;
typedef __attribute__((ext_vector_type(2))) unsigned long long ull2;

// ---------------- K1: full per-gaussian preprocess, once globally -----------
// cull[i] = {mu, mv, eu2, ev2}: exact ellipse-AABB extents (uv^2, log2 units).
// p0[i] = {mu, mv, iaP, ibP}  p1[i] = {idP, opa_eff, c0, c1}  p2[i] = {c2, rr}
__global__ __launch_bounds__(128) void prep_k(
    const float* __restrict__ pos, const float* __restrict__ rgb,
    const float* __restrict__ opa, const float* __restrict__ quat,
    const float* __restrict__ scale, const float* __restrict__ rot,
    const float* __restrict__ tran,
    float4* __restrict__ cull, float4* __restrict__ p0a,
    float4* __restrict__ p1a, float2* __restrict__ p2a)
{
    int i = blockIdx.x * blockDim.x + threadIdx.x;
    if (i >= N_G) return;

    float R00=rot[0],R01=rot[1],R02=rot[2];
    float R10=rot[3],R11=rot[4],R12=rot[5];
    float R20=rot[6],R21=rot[7],R22=rot[8];
    float t0=tran[0], t1=tran[1], t2=tran[2];

    float p0 = pos[i*3+0], p1 = pos[i*3+1], p2 = pos[i*3+2];
    float x = R00*p0 + R01*p1 + R02*p2 + t0;
    float y = R10*p0 + R11*p1 + R12*p2 + t1;
    float z = R20*p0 + R21*p1 + R22*p2 + t2;
    float rr = sqrtf(x*x + y*y + z*z);
    float invz = 1.0f/z;
    float mu = x*invz, mv = y*invz;

    float J02 = -x*invz*invz, J12 = -y*invz*invz;
    float JW00 = invz*R00 + J02*R20;
    float JW01 = invz*R01 + J02*R21;
    float JW02 = invz*R02 + J02*R22;
    float JW10 = invz*R10 + J12*R20;
    float JW11 = invz*R11 + J12*R21;
    float JW12 = invz*R12 + J12*R22;

    float qw=quat[i*4+0], qx=quat[i*4+1], qy=quat[i*4+2], qz=quat[i*4+3];
    float qn = sqrtf(qw*qw+qx*qx+qy*qy+qz*qz) + 1e-12f;
    float qi = 1.0f/qn;
    qw*=qi; qx*=qi; qy*=qi; qz*=qi;
    float Q00=1.f-2.f*(qy*qy+qz*qz), Q01=2.f*(qx*qy-qw*qz), Q02=2.f*(qx*qz+qw*qy);
    float Q10=2.f*(qx*qy+qw*qz), Q11=1.f-2.f*(qx*qx+qz*qz), Q12=2.f*(qy*qz-qw*qx);
    float Q20=2.f*(qx*qz-qw*qy), Q21=2.f*(qy*qz+qw*qx), Q22=1.f-2.f*(qx*qx+qy*qy);

    float sa=fabsf(scale[i*3+0])+1e-4f;
    float sb=fabsf(scale[i*3+1])+1e-4f;
    float sc=fabsf(scale[i*3+2])+1e-4f;
    float A00=Q00*sa,A01=Q01*sb,A02=Q02*sc;
    float A10=Q10*sa,A11=Q11*sb,A12=Q12*sc;
    float A20=Q20*sa,A21=Q21*sb,A22=Q22*sc;
    float C00=A00*A00+A01*A01+A02*A02;
    float C01=A00*A10+A01*A11+A02*A12;
    float C02=A00*A20+A01*A21+A02*A22;
    float C11=A10*A10+A11*A11+A12*A12;
    float C12=A10*A20+A11*A21+A12*A22;
    float C22=A20*A20+A21*A21+A22*A22;
    float M00=JW00*C00+JW01*C01+JW02*C02;
    float M01=JW00*C01+JW01*C11+JW02*C12;
    float M02=JW00*C02+JW01*C12+JW02*C22;
    float M10=JW10*C00+JW11*C01+JW12*C02;
    float M11=JW10*C01+JW11*C11+JW12*C12;
    float M12=JW10*C02+JW11*C12+JW12*C22;
    float a  = M00*JW00+M01*JW01+M02*JW02 + EPSV;
    float d  = M10*JW10+M11*JW11+M12*JW12 + EPSV;
    float bb = 0.5f*((M00*JW10+M01*JW11+M02*JW12)+(M10*JW00+M11*JW01+M12*JW02));
    float invdet = 1.0f/(a*d - bb*bb);
    float iaP = -0.5f*d*invdet*LOG2E;
    float ibP =  bb*invdet*LOG2E;
    float idP = -0.5f*a*invdet*LOG2E;

    float sig_o = 1.0f/(1.0f+__expf(-opa[i]));
    float opa_eff = (z > NEARP) ? sig_o : 0.0f;
    float c0 = 1.0f/(1.0f+__expf(-rgb[i*3+0]));
    float c1 = 1.0f/(1.0f+__expf(-rgb[i*3+1]));
    float c2 = 1.0f/(1.0f+__expf(-rgb[i*3+2]));

    // exact ellipse-AABB extents: eu2 = K*q11/detQ, ev2 = K*q00/detQ
    float q00 = -iaP, q01 = -0.5f*ibP, q11 = -idP;
    float detQ = q00*q11 - q01*q01;
    float K = CULL_K + log2f(opa_eff);     // -inf when opa_eff==0
    float eu2, ev2;
    if (detQ > 0.0f && K > 0.0f)      { eu2 = K*q11/detQ; ev2 = K*q00/detQ; }
    else if (K > 0.0f)                { eu2 = 1e30f; ev2 = 1e30f; }  // degenerate: keep
    else                              { eu2 = -1.0f; ev2 = -1.0f; }  // cull everywhere

    cull[i] = make_float4(mu, mv, eu2, ev2);
    p0a[i]  = make_float4(mu, mv, iaP, ibP);
    p1a[i]  = make_float4(idP, opa_eff, c0, c1);
    p2a[i]  = make_float2(c2, rr);
}

// ---------------- K2: per-tile exact cull + gather + sort + composite -------
__global__ __launch_bounds__(NTHR, 1) void render_k(
    const float4* __restrict__ cull, const float4* __restrict__ p0a,
    const float4* __restrict__ p1a, const float2* __restrict__ p2a,
    float* __restrict__ out)
{
    __shared__ __align__(16) ull skey[CAP+2];
    __shared__ int sslot[CAP];
    __shared__ float4 g0[CAP], g1[CAP];
    __shared__ float  g2[CAP];
    __shared__ float4 pix[NSEG*NPX];
    __shared__ int psum[4][CAP];
    __shared__ int cnt_sh;

    const int t = threadIdx.x;
    const int tile = blockIdx.x;
    const int tx = tile % TILES_X, ty = tile / TILES_X;
    const float u0 = ((float)(tx*TILE) + 0.5f - 48.0f) * FXI;
    const float u1 = u0 + (TILE-1) * FXI;
    const float v0 = ((float)(ty*TILE) + 0.5f - 48.0f) * FXI;
    const float v1 = v0 + (TILE-1) * FXI;
    const int wid = t >> 6, lane = t & 63;

    if (t == 0) cnt_sh = 0;
    __syncthreads();

    // ---- exact cull (coalesced f4 stream) + immediate gather-compact ----
    #pragma unroll
    for (int k = 0; k < N_G/NTHR; k++) {
        int gi = k*NTHR + t;
        float4 cq = cull[gi];
        float cu = fminf(fmaxf(cq.x, u0), u1);
        float cv = fminf(fmaxf(cq.y, v0), v1);
        float ddx = cq.x - cu, ddy = cq.y - cv;
        bool flag = (ddx*ddx <= cq.z) && (ddy*ddy <= cq.w);  // NaN -> false

        ull m = __ballot(flag);
        int nm = __popcll(m);
        int base = 0;
        if (lane == 0 && nm) base = atomicAdd(&cnt_sh, nm);
        base = __shfl(base, 0);
        if (flag) {
            int p = base + __popcll(m & ((1ull << lane) - 1ull));
            if (p < CAP) {
                float4 a0 = p0a[gi];
                float4 a1 = p1a[gi];
                float2 a2 = p2a[gi];
                g0[p] = a0; g1[p] = a1; g2[p] = a2.x;
                // key = (rr_bits, gi): globally unique -> reference's stable
                // argsort order restricted to survivors
                skey[p] = ((ull)__float_as_uint(a2.y) << 32) | (unsigned int)gi;
            }
        }
    }
    __syncthreads();
    int cnt = cnt_sh; if (cnt > CAP) cnt = CAP;

    // ---- rank sort; 4 groups x 256 threads, 2 elements/thread ----
    if (t == 0 && (cnt & 1)) skey[cnt] = ~0ull;  // pad sorts last, never scattered
    __syncthreads();
    int cnt2 = cnt + (cnt & 1);
    int nq = cnt2 >> 1;                          // total ull2 words
    const ull2* sk2 = (const ull2*)skey;
    const int g = t >> 8, e = t & 255;
    const bool h1 = (e < cnt), h2 = (e + 256 < cnt);
    ull kv1 = 0, kv2 = 0;
    if (h1) {
        kv1 = skey[e];
        if (h2) kv2 = skey[e + 256];
        int wA = (nq * g) >> 2;
        int wB = (nq * (g+1)) >> 2;
        int c1 = 0, c2 = 0;
        for (int w = wA; w < wB; w++) {
            ull2 p = sk2[w];                     // broadcast: shared by both elems
            c1 += (p.x < kv1) ? 1 : 0;
            c1 += (p.y < kv1) ? 1 : 0;
            c2 += (p.x < kv2) ? 1 : 0;
            c2 += (p.y < kv2) ? 1 : 0;
        }
        psum[g][e] = c1;
        if (h2) psum[g][e + 256] = c2;
    }
    __syncthreads();
    if (t < 256 && h1) {
        int r1 = psum[0][e] + psum[1][e] + psum[2][e] + psum[3][e];
        skey[r1]  = kv1;
        sslot[r1] = e;
        if (h2) {
            int e2 = e + 256;
            int r2 = psum[0][e2] + psum[1][e2] + psum[2][e2] + psum[3][e2];
            skey[r2]  = kv2;
            sslot[r2] = e2;
        }
    }
    __syncthreads();

    // ---- wave-aligned 16-way segmented composite (broadcast LDS reads) ----
    {
        const int seg = wid;
        const bool act = (lane < NPX);
        const int pid = act ? lane : 0;
        const int px = tx*TILE + (pid % TILE);
        const int py = ty*TILE + (pid / TILE);
        const float pu = ((float)px + 0.5f - 48.0f) * FXI;
        const float pv = ((float)py + 0.5f - 48.0f) * FXI;

        const int per = (cnt + NSEG - 1) / NSEG;
        const int sA = min(seg * per, cnt);
        const int sB = min(sA + per, cnt);

        float T = 1.0f, cr = 0.0f, cg = 0.0f, cb = 0.0f;
        for (int s = sA; s < sB; s++) {
            int slot = sslot[s];
            float4 a0 = g0[slot];
            float4 a1 = g1[slot];
            float  a2 = g2[slot];
            float dx = pu - a0.x;
            float dy = pv - a0.y;
            float pw = dx*(a0.z*dx + a0.w*dy) + a1.x*dy*dy;   // log2-scaled
            float al = fminf(a1.y * __builtin_amdgcn_exp2f(pw), 0.99f);
            float w = T * al;
            cr += w * a1.z;
            cg += w * a1.w;
            cb += w * a2;
            T *= (1.0f - al);
        }
        if (act) pix[seg*NPX + pid] = make_float4(cr, cg, cb, T);
    }
    __syncthreads();

    // ---- merge 16 depth segments front-to-back, store ----
    if (t < NPX) {
        float orr = 0.0f, og = 0.0f, ob = 0.0f, T2 = 1.0f;
        #pragma unroll
        for (int s = 0; s < NSEG; s++) {
            float4 P = pix[s*NPX + t];
            orr += T2 * P.x;
            og  += T2 * P.y;
            ob  += T2 * P.z;
            T2  *= P.w;
        }
        int px = tx*TILE + (t % TILE);
        int py = ty*TILE + (t / TILE);
        int pixel = py * IMW + px;
        out[pixel*3+0] = orr;
        out[pixel*3+1] = og;
        out[pixel*3+2] = ob;
    }
}

extern "C" void kernel_launch(void* const* d_in, const int* in_sizes, int n_in,
                              void* d_out, int out_size, void* d_ws, size_t ws_size,
                              hipStream_t stream) {
    const float* pos   = (const float*)d_in[0];
    const float* rgb   = (const float*)d_in[1];
    const float* opa   = (const float*)d_in[2];
    const float* quat  = (const float*)d_in[3];
    const float* scale = (const float*)d_in[4];
    const float* rot   = (const float*)d_in[5];
    const float* tran  = (const float*)d_in[6];
    float* out = (float*)d_out;

    char* ws = (char*)d_ws;
    float4* cull = (float4*)ws;                    // 64 KB
    float4* p0a  = (float4*)(ws + 65536);          // 64 KB
    float4* p1a  = (float4*)(ws + 131072);         // 64 KB
    float2* p2a  = (float2*)(ws + 196608);         // 32 KB

    prep_k<<<N_G/128, 128, 0, stream>>>(pos, rgb, opa, quat, scale, rot, tran,
                                        cull, p0a, p1a, p2a);
    render_k<<<NTILE, NTHR, 0, stream>>>(cull, p0a, p1a, p2a, out);
}

// Round 18
// 14.135 us; speedup vs baseline: 1.2154x; 1.2154x over previous
//
#include <hip/hip_runtime.h>
#include <math.h>

#define N_G   4096
#define IMW   96
#define TILE  6             // 6x6 px tiles
#define TILES_X 16
#define NTILE (TILES_X*TILES_X)   // 256 blocks == 256 CUs
#define NTHR  1024          // 16 waves per block
#define NW    (NTHR/64)
#define NST   (N_G/NTHR)    // 4 cull stages
#define NPX   (TILE*TILE)   // 36 pixels per tile
#define NSEG  16            // depth segments per pixel == NW
#define BCAP  1536          // max bound-phase survivors per tile
#define CAP   512           // max exact survivors per tile
#define FXI   (1.0f/96.0f)
#define NEARP 0.3f
#define EPSV  1e-8f
#define LOG2E 1.4426950408889634f
#define LN2   0.6931471805599453f
#define CULL_K 26.0f        // drop alpha < opa * 2^-26 within tile

typedef unsigned long long ull;
typedef __attribute__((ext_vector_type(2))) unsigned long long ull2;

// Single kernel, one block per 6x6 tile (256 blocks = 1/CU, 16 waves each).
// Stage pos/scale/opa into LDS via coalesced float4 (kills strided TA traffic).
// A: per-axis Frobenius bound cull from LDS -> compact gi list (no barriers)
// B: exact params (inputs from LDS stash; quat f4; rgb survivors-only) +
//    ellipse-AABB cull -> compact
// C: rank sort (4 groups x 256, 2 elems/thread)  D: wave-aligned composite
// E: merge + store.  psum/pix alias the stash (dead after B).
__global__ __launch_bounds__(NTHR, 1) void splat_k(
    const float* __restrict__ pos, const float* __restrict__ rgb,
    const float* __restrict__ opa, const float* __restrict__ quat,
    const float* __restrict__ scale, const float* __restrict__ rot,
    const float* __restrict__ tran, float* __restrict__ out)
{
    __shared__ float spos[N_G*3];        // 48 KB (psum/pix alias after B)
    __shared__ float sscale[N_G*3];      // 48 KB
    __shared__ float sopa[N_G];          // 16 KB
    __shared__ unsigned int bl[BCAP];    // 6 KB
    __shared__ __align__(16) ull skey[CAP+2];
    __shared__ int sslot[CAP];
    __shared__ float4 g0[CAP], g1[CAP];
    __shared__ float  g2[CAP];
    __shared__ int bcnt_sh, cnt_sh;

    const int t = threadIdx.x;
    const int tile = blockIdx.x;
    const int tx = tile % TILES_X, ty = tile / TILES_X;
    const float u0 = ((float)(tx*TILE) + 0.5f - 48.0f) * FXI;
    const float u1 = u0 + (TILE-1) * FXI;
    const float v0 = ((float)(ty*TILE) + 0.5f - 48.0f) * FXI;
    const float v1 = v0 + (TILE-1) * FXI;
    const int wid = t >> 6, lane = t & 63;

    float R00=rot[0],R01=rot[1],R02=rot[2];
    float R10=rot[3],R11=rot[4],R12=rot[5];
    float R20=rot[6],R21=rot[7],R22=rot[8];
    float t0=tran[0], t1=tran[1], t2=tran[2];

    // ---- coalesced staging: pos/scale (3 f4 each), opa (1 f4) ----
    {
        const float4* p4 = (const float4*)pos;
        const float4* s4 = (const float4*)scale;
        const float4* o4 = (const float4*)opa;
        float4* sp4 = (float4*)spos;
        float4* ss4 = (float4*)sscale;
        float4* so4 = (float4*)sopa;
        #pragma unroll
        for (int k = 0; k < 3; k++) {
            sp4[k*NTHR + t] = p4[k*NTHR + t];
            ss4[k*NTHR + t] = s4[k*NTHR + t];
        }
        so4[t] = o4[t];
    }
    if (t == 0) { bcnt_sh = 0; cnt_sh = 0; }
    __syncthreads();

    // ---- Phase A: per-axis Frobenius bound cull (from LDS), barrier-free ----
    #pragma unroll
    for (int st = 0; st < NST; st++) {
        int gi = st*NTHR + t;
        float p0 = spos[gi*3+0], p1 = spos[gi*3+1], p2 = spos[gi*3+2];
        float o  = sopa[gi];
        float s0 = sscale[gi*3+0], s1 = sscale[gi*3+1], s2v = sscale[gi*3+2];

        float x = R00*p0 + R01*p1 + R02*p2 + t0;
        float y = R10*p0 + R11*p1 + R12*p2 + t1;
        float z = R20*p0 + R21*p1 + R22*p2 + t2;
        float invz = 1.0f/z;
        float mu = x*invz, mv = y*invz;

        // per-axis row norms of J (== of J*W, W orthonormal):
        // ||row0||^2 = 1/z^2 + x^2/z^4 ; ||row1||^2 = 1/z^2 + y^2/z^4
        float inz2 = invz*invz;
        float fnu = inz2 + x*x*inz2*inz2;
        float fnv = inz2 + y*y*inz2*inz2;
        float smax = fmaxf(fmaxf(fabsf(s0), fabsf(s1)), fabsf(s2v)) + 1e-4f;
        float s2 = smax*smax;
        float amp = CULL_K + 1.0f + fminf(0.0f, o*LOG2E);
        float sc2 = amp * (2.0f*LN2) * 1.02f;
        float eu2b = sc2 * (fnu*s2 + EPSV);
        float ev2b = sc2 * (fnv*s2 + EPSV);

        float cu = fminf(fmaxf(mu, u0), u1);
        float cv = fminf(fmaxf(mv, v0), v1);
        float ddx = mu - cu, ddy = mv - cv;
        bool flag = (z > NEARP) && (amp > 0.0f) &&
                    (ddx*ddx <= eu2b) && (ddy*ddy <= ev2b);

        ull m = __ballot(flag);
        int nm = __popcll(m);
        int base = 0;
        if (lane == 0 && nm) base = atomicAdd(&bcnt_sh, nm);
        base = __shfl(base, 0);
        if (flag) {
            int p = base + __popcll(m & ((1ull << lane) - 1ull));
            if (p < BCAP) bl[p] = (unsigned int)gi;
        }
    }
    __syncthreads();
    int bcnt = bcnt_sh; if (bcnt > BCAP) bcnt = BCAP;

    // ---- Phase B: exact params (LDS inputs) + ellipse-AABB cull ----
    for (int s0i = 0; s0i < bcnt; s0i += NTHR) {
        int s = s0i + t;
        bool flag = false;
        float4 o0, o1; float ocb = 0.0f, rr = 0.0f;
        unsigned int gi = 0;
        if (s < bcnt) {
            gi = bl[s];
            float p0 = spos[gi*3+0], p1 = spos[gi*3+1], p2 = spos[gi*3+2];
            float x = R00*p0 + R01*p1 + R02*p2 + t0;
            float y = R10*p0 + R11*p1 + R12*p2 + t1;
            float z = R20*p0 + R21*p1 + R22*p2 + t2;
            rr = sqrtf(x*x + y*y + z*z);
            float invz = 1.0f/z;
            float mu = x*invz, mv = y*invz;

            float J02 = -x*invz*invz, J12 = -y*invz*invz;
            float JW00 = invz*R00 + J02*R20;
            float JW01 = invz*R01 + J02*R21;
            float JW02 = invz*R02 + J02*R22;
            float JW10 = invz*R10 + J12*R20;
            float JW11 = invz*R11 + J12*R21;
            float JW12 = invz*R12 + J12*R22;

            const float4 qv = ((const float4*)quat)[gi];
            float qw=qv.x, qx=qv.y, qy=qv.z, qz=qv.w;
            float qn = sqrtf(qw*qw+qx*qx+qy*qy+qz*qz) + 1e-12f;
            float qi = 1.0f/qn;
            qw*=qi; qx*=qi; qy*=qi; qz*=qi;
            float Q00=1.f-2.f*(qy*qy+qz*qz), Q01=2.f*(qx*qy-qw*qz), Q02=2.f*(qx*qz+qw*qy);
            float Q10=2.f*(qx*qy+qw*qz), Q11=1.f-2.f*(qx*qx+qz*qz), Q12=2.f*(qy*qz-qw*qx);
            float Q20=2.f*(qx*qz-qw*qy), Q21=2.f*(qy*qz+qw*qx), Q22=1.f-2.f*(qx*qx+qy*qy);

            float sa=fabsf(sscale[gi*3+0])+1e-4f;
            float sb=fabsf(sscale[gi*3+1])+1e-4f;
            float sc=fabsf(sscale[gi*3+2])+1e-4f;
            float A00=Q00*sa,A01=Q01*sb,A02=Q02*sc;
            float A10=Q10*sa,A11=Q11*sb,A12=Q12*sc;
            float A20=Q20*sa,A21=Q21*sb,A22=Q22*sc;
            float C00=A00*A00+A01*A01+A02*A02;
            float C01=A00*A10+A01*A11+A02*A12;
            float C02=A00*A20+A01*A21+A02*A22;
            float C11=A10*A10+A11*A11+A12*A12;
            float C12=A10*A20+A11*A21+A12*A22;
            float C22=A20*A20+A21*A21+A22*A22;
            float M00=JW00*C00+JW01*C01+JW02*C02;
            float M01=JW00*C01+JW01*C11+JW02*C12;
            float M02=JW00*C02+JW01*C12+JW02*C22;
            float M10=JW10*C00+JW11*C01+JW12*C02;
            float M11=JW10*C01+JW11*C11+JW12*C12;
            float M12=JW10*C02+JW11*C12+JW12*C22;
            float a  = M00*JW00+M01*JW01+M02*JW02 + EPSV;
            float d  = M10*JW10+M11*JW11+M12*JW12 + EPSV;
            float bb = 0.5f*((M00*JW10+M01*JW11+M02*JW12)+(M10*JW00+M11*JW01+M12*JW02));
            float invdet = 1.0f/(a*d - bb*bb);
            float iaP = -0.5f*d*invdet*LOG2E;
            float ibP =  bb*invdet*LOG2E;
            float idP = -0.5f*a*invdet*LOG2E;

            float sig_o = 1.0f/(1.0f+__expf(-sopa[gi]));
            float opa_eff = (z > NEARP) ? sig_o : 0.0f;

            // exact ellipse-AABB cull: extent_u^2 = K*q11/detQ etc.
            float q00 = -iaP, q01 = -0.5f*ibP, q11 = -idP;
            float detQ = q00*q11 - q01*q01;
            float K = CULL_K + log2f(opa_eff);   // -inf when opa_eff==0

            float cu = fminf(fmaxf(mu, u0), u1);
            float cv = fminf(fmaxf(mv, v0), v1);
            float ddx = mu - cu, ddy = mv - cv;
            flag = (ddx*ddx*detQ <= K*q11) && (ddy*ddy*detQ <= K*q00);

            if (flag) {
                float c0 = 1.0f/(1.0f+__expf(-rgb[gi*3+0]));
                float c1 = 1.0f/(1.0f+__expf(-rgb[gi*3+1]));
                float c2 = 1.0f/(1.0f+__expf(-rgb[gi*3+2]));
                o0 = make_float4(mu, mv, iaP, ibP);
                o1 = make_float4(idP, opa_eff, c0, c1);
                ocb = c2;
            }
        }
        ull m = __ballot(flag);
        int nm = __popcll(m);
        int base = 0;
        if (lane == 0 && nm) base = atomicAdd(&cnt_sh, nm);
        base = __shfl(base, 0);
        if (flag) {
            int p = base + __popcll(m & ((1ull << lane) - 1ull));
            if (p < CAP) {
                g0[p] = o0; g1[p] = o1; g2[p] = ocb;
                // key = (rr_bits, gi): globally unique -> reference's stable
                // argsort order restricted to survivors
                skey[p] = ((ull)__float_as_uint(rr) << 32) | gi;
            }
        }
    }
    __syncthreads();
    int cnt = cnt_sh; if (cnt > CAP) cnt = CAP;

    // stash is dead from here; alias psum/pix onto it (barrier-separated)
    int (*psum)[CAP] = (int (*)[CAP])(void*)spos;        // 8 KB
    float4* pix = (float4*)(void*)(spos + 2048);         // 9 KB

    // ---- Phase C: rank sort; 4 groups x 256 threads, 2 elements/thread ----
    if (t == 0 && (cnt & 1)) skey[cnt] = ~0ull;  // pad sorts last, never scattered
    __syncthreads();
    int cnt2 = cnt + (cnt & 1);
    int nq = cnt2 >> 1;                          // total ull2 words
    const ull2* sk2 = (const ull2*)skey;
    const int g = t >> 8, e = t & 255;
    const bool h1 = (e < cnt), h2 = (e + 256 < cnt);
    ull kv1 = 0, kv2 = 0;
    if (h1) {
        kv1 = skey[e];
        if (h2) kv2 = skey[e + 256];
        int wA = (nq * g) >> 2;
        int wB = (nq * (g+1)) >> 2;
        int c1 = 0, c2 = 0;
        for (int w = wA; w < wB; w++) {
            ull2 p = sk2[w];                     // broadcast: shared by both elems
            c1 += (p.x < kv1) ? 1 : 0;
            c1 += (p.y < kv1) ? 1 : 0;
            c2 += (p.x < kv2) ? 1 : 0;
            c2 += (p.y < kv2) ? 1 : 0;
        }
        psum[g][e] = c1;
        if (h2) psum[g][e + 256] = c2;
    }
    __syncthreads();
    if (t < 256 && h1) {
        int r1 = psum[0][e] + psum[1][e] + psum[2][e] + psum[3][e];
        skey[r1]  = kv1;
        sslot[r1] = e;
        if (h2) {
            int e2 = e + 256;
            int r2 = psum[0][e2] + psum[1][e2] + psum[2][e2] + psum[3][e2];
            skey[r2]  = kv2;
            sslot[r2] = e2;
        }
    }
    __syncthreads();

    // ---- Phase D: wave-aligned 16-way segmented composite ----
    {
        const int seg = wid;
        const bool act = (lane < NPX);
        const int pid = act ? lane : 0;
        const int px = tx*TILE + (pid % TILE);
        const int py = ty*TILE + (pid / TILE);
        const float pu = ((float)px + 0.5f - 48.0f) * FXI;
        const float pv = ((float)py + 0.5f - 48.0f) * FXI;

        const int per = (cnt + NSEG - 1) / NSEG;
        const int sA = min(seg * per, cnt);
        const int sB = min(sA + per, cnt);

        float T = 1.0f, cr = 0.0f, cg = 0.0f, cb = 0.0f;
        for (int s = sA; s < sB; s++) {
            int slot = sslot[s];                 // broadcast (uniform s)
            float4 a0 = g0[slot];
            float4 a1 = g1[slot];
            float  a2 = g2[slot];
            float dx = pu - a0.x;
            float dy = pv - a0.y;
            float pw = dx*(a0.z*dx + a0.w*dy) + a1.x*dy*dy;   // log2-scaled
            float al = fminf(a1.y * __builtin_amdgcn_exp2f(pw), 0.99f);
            float w = T * al;
            cr += w * a1.z;
            cg += w * a1.w;
            cb += w * a2;
            T *= (1.0f - al);
        }
        if (act) pix[seg*NPX + pid] = make_float4(cr, cg, cb, T);
    }
    __syncthreads();

    // ---- Phase E: merge 16 depth segments front-to-back, store ----
    if (t < NPX) {
        float orr = 0.0f, og = 0.0f, ob = 0.0f, T2 = 1.0f;
        #pragma unroll
        for (int s = 0; s < NSEG; s++) {
            float4 P = pix[s*NPX + t];
            orr += T2 * P.x;
            og  += T2 * P.y;
            ob  += T2 * P.z;
            T2  *= P.w;
        }
        int px = tx*TILE + (t % TILE);
        int py = ty*TILE + (t / TILE);
        int pixel = py * IMW + px;
        out[pixel*3+0] = orr;
        out[pixel*3+1] = og;
        out[pixel*3+2] = ob;
    }
}

extern "C" void kernel_launch(void* const* d_in, const int* in_sizes, int n_in,
                              void* d_out, int out_size, void* d_ws, size_t ws_size,
                              hipStream_t stream) {
    const float* pos   = (const float*)d_in[0];
    const float* rgb   = (const float*)d_in[1];
    const float* opa   = (const float*)d_in[2];
    const float* quat  = (const float*)d_in[3];
    const float* scale = (const float*)d_in[4];
    const float* rot   = (const float*)d_in[5];
    const float* tran  = (const float*)d_in[6];
    float* out = (float*)d_out;

    splat_k<<<NTILE, NTHR, 0, stream>>>(pos, rgb, opa, quat, scale, rot, tran, out);
}

// Round 19
// 13.538 us; speedup vs baseline: 1.2690x; 1.0441x over previous
//
#include <hip/hip_runtime.h>
#include <hip/hip_fp16.h>
#include <math.h>

#define N_G   4096
#define IMW   96
#define TILE  6             // 6x6 px tiles
#define TILES_X 16
#define NTILE (TILES_X*TILES_X)   // 256 blocks == 256 CUs
#define NTHR  1024          // 16 waves per block
#define NW    (NTHR/64)
#define NST   (N_G/NTHR)    // 4 cull stages
#define NPX   (TILE*TILE)   // 36 pixels per tile
#define NSEG  16            // depth segments per pixel == NW
#define BCAP  1536          // max bound-phase survivors per tile
#define CAP   512           // max exact survivors per tile
#define FXI   (1.0f/96.0f)
#define NEARP 0.3f
#define EPSV  1e-8f
#define LOG2E 1.4426950408889634f
#define LN2   0.6931471805599453f
#define CULL_K 16.0f        // drop alpha < opa * 2^-16 within tile

typedef unsigned long long ull;
typedef __attribute__((ext_vector_type(2))) unsigned long long ull2;

// Single kernel, one block per 6x6 tile (256 blocks = 1/CU, 16 waves each).
// A: cheap conservative bound cull (prefetched coalesced loads) -> gi list
// B: exact params + ellipse-AABB cull -> PACKED params (f16 colors) at slot p
// C: rank sort by (rr_bits,gi); scatter permutes the PARAM PAYLOAD into
//    depth order (no indirection table)
// D: wave-aligned composite: 2 sequential broadcast b128 reads per element
// E: merge + store.
__global__ __launch_bounds__(NTHR, 1) void splat_k(
    const float* __restrict__ pos, const float* __restrict__ rgb,
    const float* __restrict__ opa, const float* __restrict__ quat,
    const float* __restrict__ scale, const float* __restrict__ rot,
    const float* __restrict__ tran, float* __restrict__ out)
{
    __shared__ unsigned int bl[BCAP];
    __shared__ __align__(16) ull skey[CAP+2];
    __shared__ float4 pk0[CAP], pk1[CAP];     // unsorted packed params
    __shared__ float4 pk0s[CAP], pk1s[CAP];   // depth-sorted packed params
    __shared__ float4 pix[NSEG*NPX];
    __shared__ int psum[4][CAP];
    __shared__ int bcnt_sh, cnt_sh;

    const int t = threadIdx.x;
    const int tile = blockIdx.x;
    const int tx = tile % TILES_X, ty = tile / TILES_X;
    const float u0 = ((float)(tx*TILE) + 0.5f - 48.0f) * FXI;
    const float u1 = u0 + (TILE-1) * FXI;
    const float v0 = ((float)(ty*TILE) + 0.5f - 48.0f) * FXI;
    const float v1 = v0 + (TILE-1) * FXI;
    const int wid = t >> 6, lane = t & 63;

    if (t == 0) { bcnt_sh = 0; cnt_sh = 0; }

    float R00=rot[0],R01=rot[1],R02=rot[2];
    float R10=rot[3],R11=rot[4],R12=rot[5];
    float R20=rot[6],R21=rot[7],R22=rot[8];
    float t0=tran[0], t1=tran[1], t2=tran[2];

    // ---- Phase A prefetch: issue all 4 stages' loads up front ----
    float pp0[NST], pp1[NST], pp2[NST], po[NST], ps0[NST], ps1[NST], ps2[NST];
    #pragma unroll
    for (int st = 0; st < NST; st++) {
        int gi = st*NTHR + t;
        pp0[st]=pos[gi*3+0]; pp1[st]=pos[gi*3+1]; pp2[st]=pos[gi*3+2];
        po[st]=opa[gi];
        ps0[st]=scale[gi*3+0]; ps1[st]=scale[gi*3+1]; ps2[st]=scale[gi*3+2];
    }
    __syncthreads();   // counters initialized

    // ---- Phase A: cheap conservative bound cull, barrier-free compact ----
    #pragma unroll
    for (int st = 0; st < NST; st++) {
        int gi = st*NTHR + t;
        float x = R00*pp0[st] + R01*pp1[st] + R02*pp2[st] + t0;
        float y = R10*pp0[st] + R11*pp1[st] + R12*pp2[st] + t1;
        float z = R20*pp0[st] + R21*pp1[st] + R22*pp2[st] + t2;
        float invz = 1.0f/z;
        float mu = x*invz, mv = y*invz;

        // ||J*W||_F^2 == ||J||_F^2 (W orthonormal): 2/z^2 + (x^2+y^2)/z^4
        float inz2 = invz*invz;
        float fn = 2.0f*inz2 + (x*x + y*y)*inz2*inz2;
        float smax = fmaxf(fmaxf(fabsf(ps0[st]), fabsf(ps1[st])), fabsf(ps2[st])) + 1e-4f;
        float lmax = fn*smax*smax + EPSV;      // >= lam_max(cov2d)
        float amp = CULL_K + 1.0f + fminf(0.0f, po[st]*LOG2E);
        float r2b = amp * lmax * (2.0f*LN2) * 1.02f;

        float cu = fminf(fmaxf(mu, u0), u1);
        float cv = fminf(fmaxf(mv, v0), v1);
        float ddx = mu - cu, ddy = mv - cv;
        bool flag = (z > NEARP) && (amp > 0.0f) && (ddx*ddx + ddy*ddy <= r2b);

        ull m = __ballot(flag);
        int nm = __popcll(m);
        int base = 0;
        if (lane == 0 && nm) base = atomicAdd(&bcnt_sh, nm);
        base = __shfl(base, 0);
        if (flag) {
            int p = base + __popcll(m & ((1ull << lane) - 1ull));
            if (p < BCAP) bl[p] = (unsigned int)gi;
        }
    }
    __syncthreads();
    int bcnt = bcnt_sh; if (bcnt > BCAP) bcnt = BCAP;

    // ---- Phase B: exact params + ellipse-AABB cull, packed write ----
    for (int s0i = 0; s0i < bcnt; s0i += NTHR) {
        int s = s0i + t;
        bool flag = false;
        float4 o0, o1; float rr = 0.0f;
        unsigned int gi = 0;
        if (s < bcnt) {
            gi = bl[s];
            float p0=pos[gi*3+0], p1=pos[gi*3+1], p2=pos[gi*3+2];
            float x = R00*p0 + R01*p1 + R02*p2 + t0;
            float y = R10*p0 + R11*p1 + R12*p2 + t1;
            float z = R20*p0 + R21*p1 + R22*p2 + t2;
            rr = sqrtf(x*x + y*y + z*z);
            float invz = 1.0f/z;
            float mu = x*invz, mv = y*invz;

            float J02 = -x*invz*invz, J12 = -y*invz*invz;
            float JW00 = invz*R00 + J02*R20;
            float JW01 = invz*R01 + J02*R21;
            float JW02 = invz*R02 + J02*R22;
            float JW10 = invz*R10 + J12*R20;
            float JW11 = invz*R11 + J12*R21;
            float JW12 = invz*R12 + J12*R22;

            float qw=quat[gi*4+0], qx=quat[gi*4+1], qy=quat[gi*4+2], qz=quat[gi*4+3];
            float qn = sqrtf(qw*qw+qx*qx+qy*qy+qz*qz) + 1e-12f;
            float qi = 1.0f/qn;
            qw*=qi; qx*=qi; qy*=qi; qz*=qi;
            float Q00=1.f-2.f*(qy*qy+qz*qz), Q01=2.f*(qx*qy-qw*qz), Q02=2.f*(qx*qz+qw*qy);
            float Q10=2.f*(qx*qy+qw*qz), Q11=1.f-2.f*(qx*qx+qz*qz), Q12=2.f*(qy*qz-qw*qx);
            float Q20=2.f*(qx*qz-qw*qy), Q21=2.f*(qy*qz+qw*qx), Q22=1.f-2.f*(qx*qx+qy*qy);

            float sa=fabsf(scale[gi*3+0])+1e-4f;
            float sb=fabsf(scale[gi*3+1])+1e-4f;
            float sc=fabsf(scale[gi*3+2])+1e-4f;
            float A00=Q00*sa,A01=Q01*sb,A02=Q02*sc;
            float A10=Q10*sa,A11=Q11*sb,A12=Q12*sc;
            float A20=Q20*sa,A21=Q21*sb,A22=Q22*sc;
            float C00=A00*A00+A01*A01+A02*A02;
            float C01=A00*A10+A01*A11+A02*A12;
            float C02=A00*A20+A01*A21+A02*A22;
            float C11=A10*A10+A11*A11+A12*A12;
            float C12=A10*A20+A11*A21+A12*A22;
            float C22=A20*A20+A21*A21+A22*A22;
            float M00=JW00*C00+JW01*C01+JW02*C02;
            float M01=JW00*C01+JW01*C11+JW02*C12;
            float M02=JW00*C02+JW01*C12+JW02*C22;
            float M10=JW10*C00+JW11*C01+JW12*C02;
            float M11=JW10*C01+JW11*C11+JW12*C12;
            float M12=JW10*C02+JW11*C12+JW12*C22;
            float a  = M00*JW00+M01*JW01+M02*JW02 + EPSV;
            float d  = M10*JW10+M11*JW11+M12*JW12 + EPSV;
            float bb = 0.5f*((M00*JW10+M01*JW11+M02*JW12)+(M10*JW00+M11*JW01+M12*JW02));
            float invdet = 1.0f/(a*d - bb*bb);
            float iaP = -0.5f*d*invdet*LOG2E;
            float ibP =  bb*invdet*LOG2E;
            float idP = -0.5f*a*invdet*LOG2E;

            float sig_o = 1.0f/(1.0f+__expf(-opa[gi]));
            float opa_eff = (z > NEARP) ? sig_o : 0.0f;

            // exact ellipse-AABB cull: extent_u^2 = K*q11/detQ etc.
            float q00 = -iaP, q01 = -0.5f*ibP, q11 = -idP;
            float detQ = q00*q11 - q01*q01;
            float K = CULL_K + log2f(opa_eff);   // -inf when opa_eff==0

            float cu = fminf(fmaxf(mu, u0), u1);
            float cv = fminf(fmaxf(mv, v0), v1);
            float ddx = mu - cu, ddy = mv - cv;
            flag = (ddx*ddx*detQ <= K*q11) && (ddy*ddy*detQ <= K*q00);

            if (flag) {
                float c0 = 1.0f/(1.0f+__expf(-rgb[gi*3+0]));
                float c1 = 1.0f/(1.0f+__expf(-rgb[gi*3+1]));
                float c2 = 1.0f/(1.0f+__expf(-rgb[gi*3+2]));
                unsigned int c01p =
                    (unsigned int)__half_as_ushort(__float2half_rn(c0)) |
                    ((unsigned int)__half_as_ushort(__float2half_rn(c1)) << 16);
                unsigned int c2p =
                    (unsigned int)__half_as_ushort(__float2half_rn(c2));
                o0 = make_float4(mu, mv, iaP, ibP);
                o1 = make_float4(idP, opa_eff,
                                 __uint_as_float(c01p), __uint_as_float(c2p));
            }
        }
        ull m = __ballot(flag);
        int nm = __popcll(m);
        int base = 0;
        if (lane == 0 && nm) base = atomicAdd(&cnt_sh, nm);
        base = __shfl(base, 0);
        if (flag) {
            int p = base + __popcll(m & ((1ull << lane) - 1ull));
            if (p < CAP) {
                pk0[p] = o0; pk1[p] = o1;
                // key = (rr_bits, gi): globally unique -> reference's stable
                // argsort order restricted to survivors
                skey[p] = ((ull)__float_as_uint(rr) << 32) | gi;
            }
        }
    }
    __syncthreads();
    int cnt = cnt_sh; if (cnt > CAP) cnt = CAP;

    // ---- Phase C: rank sort; scatter permutes PARAM PAYLOAD into order ----
    if (t == 0 && (cnt & 1)) skey[cnt] = ~0ull;  // pad sorts last, never scattered
    __syncthreads();
    int cnt2 = cnt + (cnt & 1);
    int nq = cnt2 >> 1;                          // total ull2 words
    const ull2* sk2 = (const ull2*)skey;
    const int g = t >> 8, e = t & 255;
    const bool h1 = (e < cnt), h2 = (e + 256 < cnt);
    if (h1) {
        ull kv1 = skey[e];
        ull kv2 = h2 ? skey[e + 256] : 0;
        int wA = (nq * g) >> 2;
        int wB = (nq * (g+1)) >> 2;
        int c1 = 0, c2 = 0;
        for (int w = wA; w < wB; w++) {
            ull2 p = sk2[w];                     // broadcast: shared by both elems
            c1 += (p.x < kv1) ? 1 : 0;
            c1 += (p.y < kv1) ? 1 : 0;
            c2 += (p.x < kv2) ? 1 : 0;
            c2 += (p.y < kv2) ? 1 : 0;
        }
        psum[g][e] = c1;
        if (h2) psum[g][e + 256] = c2;
    }
    __syncthreads();
    if (t < 256 && h1) {
        int r1 = psum[0][e] + psum[1][e] + psum[2][e] + psum[3][e];
        pk0s[r1] = pk0[e];
        pk1s[r1] = pk1[e];
        if (h2) {
            int e2 = e + 256;
            int r2 = psum[0][e2] + psum[1][e2] + psum[2][e2] + psum[3][e2];
            pk0s[r2] = pk0[e2];
            pk1s[r2] = pk1[e2];
        }
    }
    __syncthreads();

    // ---- Phase D: wave-aligned composite, 2 sequential broadcast b128/elem ----
    {
        const int seg = wid;
        const bool act = (lane < NPX);
        const int pid = act ? lane : 0;
        const int px = tx*TILE + (pid % TILE);
        const int py = ty*TILE + (pid / TILE);
        const float pu = ((float)px + 0.5f - 48.0f) * FXI;
        const float pv = ((float)py + 0.5f - 48.0f) * FXI;

        const int per = (cnt + NSEG - 1) / NSEG;
        const int sA = min(seg * per, cnt);
        const int sB = min(sA + per, cnt);

        float T = 1.0f, cr = 0.0f, cg = 0.0f, cb = 0.0f;
        for (int s = sA; s < sB; s++) {
            float4 a0 = pk0s[s];                 // broadcast, affine addr
            float4 a1 = pk1s[s];                 // broadcast, affine addr
            unsigned int c01p = __float_as_uint(a1.z);
            float c0 = __half2float(__ushort_as_half((unsigned short)(c01p & 0xffffu)));
            float c1 = __half2float(__ushort_as_half((unsigned short)(c01p >> 16)));
            float c2 = __half2float(__ushort_as_half((unsigned short)(__float_as_uint(a1.w) & 0xffffu)));
            float dx = pu - a0.x;
            float dy = pv - a0.y;
            float pw = dx*(a0.z*dx + a0.w*dy) + a1.x*dy*dy;   // log2-scaled
            float al = fminf(a1.y * __builtin_amdgcn_exp2f(pw), 0.99f);
            float w = T * al;
            cr += w * c0;
            cg += w * c1;
            cb += w * c2;
            T *= (1.0f - al);
        }
        if (act) pix[seg*NPX + pid] = make_float4(cr, cg, cb, T);
    }
    __syncthreads();

    // ---- Phase E: merge 16 depth segments front-to-back, store ----
    if (t < NPX) {
        float orr = 0.0f, og = 0.0f, ob = 0.0f, T2 = 1.0f;
        #pragma unroll
        for (int s = 0; s < NSEG; s++) {
            float4 P = pix[s*NPX + t];
            orr += T2 * P.x;
            og  += T2 * P.y;
            ob  += T2 * P.z;
            T2  *= P.w;
        }
        int px = tx*TILE + (t % TILE);
        int py = ty*TILE + (t / TILE);
        int pixel = py * IMW + px;
        out[pixel*3+0] = orr;
        out[pixel*3+1] = og;
        out[pixel*3+2] = ob;
    }
}

extern "C" void kernel_launch(void* const* d_in, const int* in_sizes, int n_in,
                              void* d_out, int out_size, void* d_ws, size_t ws_size,
                              hipStream_t stream) {
    const float* pos   = (const float*)d_in[0];
    const float* rgb   = (const float*)d_in[1];
    const float* opa   = (const float*)d_in[2];
    const float* quat  = (const float*)d_in[3];
    const float* scale = (const float*)d_in[4];
    const float* rot   = (const float*)d_in[5];
    const float* tran  = (const float*)d_in[6];
    float* out = (float*)d_out;

    splat_k<<<NTILE, NTHR, 0, stream>>>(pos, rgb, opa, quat, scale, rot, tran, out);
}